// Round 12
// baseline (269.854 us; speedup 1.0000x reference)
//
#include <hip/hip_runtime.h>
#include <hip/hip_bf16.h>

#define N_NODES 50000
#define N_EDGES 800000
#define N_GRAPHS 64
#define HID 64
#define SCAN_NB 196  // ceil(50000/256)
#define FILL_RANGES 8
#define RANGE_SIZE ((N_NODES + FILL_RANGES - 1) / FILL_RANGES)  // 6250

static inline size_t align256(size_t x) { return (x + 255) & ~(size_t)255; }

typedef __attribute__((ext_vector_type(8))) short short8v;
typedef __attribute__((ext_vector_type(4))) float f32x4;

// bf16 helpers (bit-level, RNE) -- storage compression + MFMA input prep.
__device__ __forceinline__ unsigned short f2bf(float f) {
    unsigned int u = __float_as_uint(f);
    unsigned int r = (u + 0x7fffu + ((u >> 16) & 1u)) >> 16;
    return (unsigned short)r;
}
__device__ __forceinline__ float bf2f(unsigned short h) {
    return __uint_as_float(((unsigned int)h) << 16);
}

// zero two disjoint int arrays in one launch (launch-count reduction)
__global__ void zero2(int* __restrict__ a, int na, int* __restrict__ b, int nb) {
    int i = blockIdx.x * blockDim.x + threadIdx.x;
    if (i < na) a[i] = 0;
    else if (i < na + nb) b[i - na] = 0;
}

// count incoming edges per destination node
__global__ void deg_kernel(const int* __restrict__ ei, int* __restrict__ cnt) {
    int e = blockIdx.x * blockDim.x + threadIdx.x;
    if (e < N_EDGES) atomicAdd(&cnt[ei[N_EDGES + e]], 1);
}

// phase A: per-block (256-wide) inclusive scan of cnt; block totals to bsum
__global__ __launch_bounds__(256) void scan_a(const int* __restrict__ cnt,
                                              int* __restrict__ incl,
                                              int* __restrict__ bsum) {
    __shared__ int sd[256];
    int t = threadIdx.x;
    int i = blockIdx.x * 256 + t;
    int v = (i < N_NODES) ? cnt[i] : 0;
    sd[t] = v;
    __syncthreads();
    for (int off = 1; off < 256; off <<= 1) {
        int u = (t >= off) ? sd[t - off] : 0;
        __syncthreads();
        sd[t] += u;
        __syncthreads();
    }
    if (i < N_NODES) incl[i] = sd[t];
    if (t == 255) bsum[blockIdx.x] = sd[255];
}

// phase B (+gstart fused): threads 0..255 do the exclusive scan of the 196
// block sums; threads 256..320 binary-search gstart (batch is sorted).
// All 384 threads execute every __syncthreads.
__global__ __launch_bounds__(384) void scan_b_gstart(const int* __restrict__ bsum,
                                                     int* __restrict__ boff,
                                                     const int* __restrict__ batch,
                                                     int* __restrict__ gstart) {
    __shared__ int sd[256];
    int t = threadIdx.x;
    int v = 0;
    if (t < 256) {
        v = (t < SCAN_NB) ? bsum[t] : 0;
        sd[t] = v;
    }
    __syncthreads();
    for (int off = 1; off < 256; off <<= 1) {
        int u = (t < 256 && t >= off) ? sd[t - off] : 0;
        __syncthreads();
        if (t < 256) sd[t] += u;
        __syncthreads();
    }
    if (t < SCAN_NB) boff[t] = sd[t] - v;  // exclusive
    if (t >= 256 && t - 256 <= N_GRAPHS) {
        int g = t - 256;
        int lo = 0, hi = N_NODES;
        while (lo < hi) {
            int mid = (lo + hi) >> 1;
            if (batch[mid] < g) lo = mid + 1; else hi = mid;
        }
        gstart[g] = lo;
    }
}

// phase C: writeback row_ptr / fill_ptr / dinv
__global__ void scan_c(const int* __restrict__ cnt, const int* __restrict__ incl,
                       const int* __restrict__ boff, int* __restrict__ row_ptr,
                       int* __restrict__ fill_ptr, float* __restrict__ dinv) {
    int i = blockIdx.x * blockDim.x + threadIdx.x;
    if (i < N_NODES) {
        int c = cnt[i];
        int run = boff[i >> 8] + incl[i];  // inclusive prefix over all nodes
        row_ptr[i + 1] = run;
        fill_ptr[i] = run - c;             // bucket start
        dinv[i] = rsqrtf((float)c + 1.0f);
        if (i == 0) row_ptr[0] = 0;
    }
}

// XCD-partitioned CSR scatter (round-8 lesson: unpartitioned random 4B
// scatter writes cost a 64B line writeback each; partition dst ranges so
// each csr region is written from one XCD and lines stay L2-resident).
__global__ __launch_bounds__(256) void fill_kernel(const int* __restrict__ ei,
                                                   int* __restrict__ fill_ptr,
                                                   int* __restrict__ csr_src) {
    int r = blockIdx.x & (FILL_RANGES - 1);
    int e = (blockIdx.x >> 3) * 256 + threadIdx.x;
    if (e >= N_EDGES) return;
    int dst = ei[N_EDGES + e];
    int lo = r * RANGE_SIZE;
    if (dst >= lo && dst < lo + RANGE_SIZE) {
        int src = ei[e];
        int pos = atomicAdd(&fill_ptr[dst], 1);
        csr_src[pos] = src;
    }
}

// MFMA matmul (layer 1 only, K=128): hw2 = bf16(dinv * (x @ W1)).
// 3-term hi/lo bf16 split keeps error at bf16^2 (~1.6e-5). W fragments
// pre-swizzled in LDS (conflict-free ds_read_b128); A per-lane from global.
// D layout (m89-verified): row=(l>>4)*4+j, col=l&15.
template <int K>
__global__ __launch_bounds__(256) void mfma_matmul(const float* __restrict__ h,
                                                   const float* __restrict__ W,
                                                   const float* __restrict__ dinv,
                                                   unsigned short* __restrict__ hw2) {
    constexpr int NSTEP = K / 32;
    __shared__ unsigned short sWH[NSTEP * 4 * 64 * 8];
    __shared__ unsigned short sWL[NSTEP * 4 * 64 * 8];
    int tid = threadIdx.x;
    int r0 = blockIdx.x * 64;

#pragma unroll 1
    for (int ent = tid; ent < NSTEP * 4 * 64; ent += 256) {
        int lane_e = ent & 63;
        int c = (ent >> 6) & 3;
        int step = ent >> 8;
        int kb = step * 32 + (lane_e >> 4) * 8;
        int n = c * 16 + (lane_e & 15);
#pragma unroll
        for (int j = 0; j < 8; ++j) {
            float f = W[(kb + j) * 64 + n];
            unsigned short hi = f2bf(f);
            sWH[ent * 8 + j] = hi;
            sWL[ent * 8 + j] = f2bf(f - bf2f(hi));
        }
    }
    __syncthreads();

    int lane = tid & 63;
    int wid = tid >> 6;
    int arow = min(r0 + wid * 16 + (lane & 15), N_NODES - 1);  // clamp; write guarded
    const float* ap = h + (size_t)arow * K;
    int klane = (lane >> 4) * 8;

    f32x4 acc[4];
#pragma unroll
    for (int c = 0; c < 4; ++c) acc[c] = (f32x4){0.f, 0.f, 0.f, 0.f};

#pragma unroll 1
    for (int step = 0; step < NSTEP; ++step) {
        int kb = step * 32 + klane;
        float4 f0 = *(const float4*)&ap[kb];
        float4 f1 = *(const float4*)&ap[kb + 4];
        float fv[8] = {f0.x, f0.y, f0.z, f0.w, f1.x, f1.y, f1.z, f1.w};
        short8v ahi, alo;
#pragma unroll
        for (int j = 0; j < 8; ++j) {
            unsigned short hi = f2bf(fv[j]);
            ahi[j] = (short)hi;
            alo[j] = (short)f2bf(fv[j] - bf2f(hi));
        }
#pragma unroll
        for (int c = 0; c < 4; ++c) {
            short8v bh = *(const short8v*)&sWH[((step * 4 + c) * 64 + lane) * 8];
            short8v bl = *(const short8v*)&sWL[((step * 4 + c) * 64 + lane) * 8];
            acc[c] = __builtin_amdgcn_mfma_f32_16x16x32_bf16(ahi, bh, acc[c], 0, 0, 0);
            acc[c] = __builtin_amdgcn_mfma_f32_16x16x32_bf16(alo, bh, acc[c], 0, 0, 0);
            acc[c] = __builtin_amdgcn_mfma_f32_16x16x32_bf16(ahi, bl, acc[c], 0, 0, 0);
        }
    }

    int rb = r0 + wid * 16 + (lane >> 4) * 4;
#pragma unroll
    for (int j = 0; j < 4; ++j) {
        int row = rb + j;
        if (row < N_NODES) {
            float dv = dinv[row];
#pragma unroll
            for (int c = 0; c < 4; ++c) {
                hw2[(size_t)row * 64 + c * 16 + (lane & 15)] = f2bf(dv * acc[c][j]);
            }
        }
    }
}

// FUSED agg + next-layer matmul. One wave per node.
// Phase 1: gather/normalize identical to agg_kernel (wave-uniform shfl
// discipline, round-5 lesson). Phase 2: the wave holds the normalized h-row
// in registers (lane&15 owns dims 4q..4q+3, duplicated across groups);
// out[col=lane] = sum_k h[k]*Wn[k][col] via unrolled shfl broadcasts +
// conflict-free LDS reads. Exact f32; output bf16 dinv-scaled (= next hw2).
// Eliminates the h f32 round-trip and the separate matmul launch.
__global__ __launch_bounds__(256) void aggmm_kernel(const unsigned short* __restrict__ hw_in,
                                                    const int* __restrict__ row_ptr,
                                                    const int* __restrict__ csr_src,
                                                    const float* __restrict__ dinv,
                                                    const float* __restrict__ b,   // current-layer bias
                                                    const float* __restrict__ Wn,  // next-layer 64x64
                                                    unsigned short* __restrict__ hw_out) {
    __shared__ float sW[64 * 64];
    int tid = threadIdx.x;
#pragma unroll 1
    for (int i = tid * 4; i < 64 * 64; i += 256 * 4)
        *(float4*)&sW[i] = *(const float4*)&Wn[i];
    __syncthreads();

    int node = blockIdx.x * 4 + (tid >> 6);
    int lane = tid & 63;
    if (node >= N_NODES) return;
    int grp = lane >> 4;
    int gl  = lane & 15;
    int s = row_ptr[node], e = row_ptr[node + 1];

    float ax = 0.f, ay = 0.f, az = 0.f, aw = 0.f;
    for (int base = s; base < e; base += 64) {
        int nE = min(64, e - base);                          // wave-uniform
        int msrc = (lane < nE) ? csr_src[base + lane] : 0;   // coalesced
#pragma unroll 2
        for (int i = 0; i < nE; i += 4) {                    // uniform trip count
            int myi = i + grp;
            int src = __shfl(msrc, myi, 64);                 // full-exec shfl
            if (myi < nE) {
                ushort4 v = *(const ushort4*)&hw_in[(size_t)src * 64 + gl * 4];
                ax += bf2f(v.x); ay += bf2f(v.y); az += bf2f(v.z); aw += bf2f(v.w);
            }
        }
    }
#pragma unroll
    for (int off = 16; off <= 32; off <<= 1) {
        ax += __shfl_xor(ax, off, 64);
        ay += __shfl_xor(ay, off, 64);
        az += __shfl_xor(az, off, 64);
        aw += __shfl_xor(aw, off, 64);
    }
    ushort4 sv = *(const ushort4*)&hw_in[(size_t)node * 64 + gl * 4];
    ax += bf2f(sv.x); ay += bf2f(sv.y); az += bf2f(sv.z); aw += bf2f(sv.w);

    float di = dinv[node];
    float4 bb = *(const float4*)&b[gl * 4];
    float vx = di * ax + bb.x;
    float vy = di * ay + bb.y;
    float vz = di * az + bb.z;
    float vw = di * aw + bb.w;

    float sq = vx * vx + vy * vy + vz * vz + vw * vw;
#pragma unroll
    for (int off = 1; off <= 8; off <<= 1) sq += __shfl_xor(sq, off, 64);
    float inv = 1.0f / fmaxf(sqrtf(sq), 1e-12f);

    float rx = fmaxf(vx * inv, 0.f);
    float ry = fmaxf(vy * inv, 0.f);
    float rz = fmaxf(vz * inv, 0.f);
    float rw = fmaxf(vw * inv, 0.f);

    // phase 2: out[lane] = sum_k h[k] * sW[k*64 + lane]
    float acc = 0.f;
#pragma unroll
    for (int q = 0; q < 16; ++q) {
        float h0 = __shfl(rx, q, 64);   // h[4q+0] lives in lane q (group 0)
        float h1 = __shfl(ry, q, 64);
        float h2 = __shfl(rz, q, 64);
        float h3 = __shfl(rw, q, 64);
        acc += h0 * sW[(4 * q + 0) * 64 + lane];
        acc += h1 * sW[(4 * q + 1) * 64 + lane];
        acc += h2 * sW[(4 * q + 2) * 64 + lane];
        acc += h3 * sW[(4 * q + 3) * 64 + lane];
    }
    hw_out[(size_t)node * 64 + lane] = f2bf(di * acc);
}

// Final agg (layer 3): same phase-1, writes normalized h rows f32 for pooling.
__global__ __launch_bounds__(256) void agg_kernel(const unsigned short* __restrict__ hw2,
                                                  const int* __restrict__ row_ptr,
                                                  const int* __restrict__ csr_src,
                                                  const float* __restrict__ dinv,
                                                  const float* __restrict__ b,
                                                  float* __restrict__ hout) {
    int node = blockIdx.x * 4 + (threadIdx.x >> 6);
    int lane = threadIdx.x & 63;
    if (node >= N_NODES) return;
    int grp = lane >> 4;
    int gl  = lane & 15;
    int s = row_ptr[node], e = row_ptr[node + 1];

    float ax = 0.f, ay = 0.f, az = 0.f, aw = 0.f;
    for (int base = s; base < e; base += 64) {
        int nE = min(64, e - base);
        int msrc = (lane < nE) ? csr_src[base + lane] : 0;
#pragma unroll 2
        for (int i = 0; i < nE; i += 4) {
            int myi = i + grp;
            int src = __shfl(msrc, myi, 64);
            if (myi < nE) {
                ushort4 v = *(const ushort4*)&hw2[(size_t)src * 64 + gl * 4];
                ax += bf2f(v.x); ay += bf2f(v.y); az += bf2f(v.z); aw += bf2f(v.w);
            }
        }
    }
#pragma unroll
    for (int off = 16; off <= 32; off <<= 1) {
        ax += __shfl_xor(ax, off, 64);
        ay += __shfl_xor(ay, off, 64);
        az += __shfl_xor(az, off, 64);
        aw += __shfl_xor(aw, off, 64);
    }
    ushort4 sv = *(const ushort4*)&hw2[(size_t)node * 64 + gl * 4];
    ax += bf2f(sv.x); ay += bf2f(sv.y); az += bf2f(sv.z); aw += bf2f(sv.w);

    float di = dinv[node];
    float4 bb = *(const float4*)&b[gl * 4];
    float vx = di * ax + bb.x;
    float vy = di * ay + bb.y;
    float vz = di * az + bb.z;
    float vw = di * aw + bb.w;

    float sq = vx * vx + vy * vy + vz * vz + vw * vw;
#pragma unroll
    for (int off = 1; off <= 8; off <<= 1) sq += __shfl_xor(sq, off, 64);
    float inv = 1.0f / fmaxf(sqrtf(sq), 1e-12f);

    if (grp == 0) {
        float4 r;
        r.x = fmaxf(vx * inv, 0.f);
        r.y = fmaxf(vy * inv, 0.f);
        r.z = fmaxf(vz * inv, 0.f);
        r.w = fmaxf(vw * inv, 0.f);
        *(float4*)&hout[(size_t)node * 64 + gl * 4] = r;
    }
}

// Phase-1 pooling: wave owns 16 consecutive nodes, lane = dim; batch sorted ->
// running (graph,sum,max) with atomic flush on transition. Post-ReLU values
// >= 0 so int-bit atomicMax is order-preserving; init-0 matches the guard.
__global__ __launch_bounds__(256) void pool_partial_kernel(const float* __restrict__ h,
                                                           const int* __restrict__ batch,
                                                           float* __restrict__ gsum,
                                                           float* __restrict__ gmax) {
    int wid = threadIdx.x >> 6, lane = threadIdx.x & 63;
    int i0 = blockIdx.x * 64 + wid * 16;
    if (i0 >= N_NODES) return;
    int i1 = min(i0 + 16, N_NODES);
    int gcur = batch[i0];
    float sum = 0.f, mx = 0.f;
    for (int i = i0; i < i1; ++i) {
        int g = batch[i];
        if (g != gcur) {
            atomicAdd(&gsum[gcur * 64 + lane], sum);
            atomicMax((int*)&gmax[gcur * 64 + lane], __float_as_int(mx));
            sum = 0.f; mx = 0.f; gcur = g;
        }
        float v = h[(size_t)i * 64 + lane];
        sum += v;
        mx = fmaxf(mx, v);
    }
    atomicAdd(&gsum[gcur * 64 + lane], sum);
    atomicMax((int*)&gmax[gcur * 64 + lane], __float_as_int(mx));
}

// Phase-2: one block per graph; mean + concat + 128x32 linear.
__global__ __launch_bounds__(128) void linear_kernel(const float* __restrict__ gsum,
                                                     const float* __restrict__ gmax,
                                                     const int* __restrict__ gstart,
                                                     const float* __restrict__ Wl,
                                                     const float* __restrict__ bl,
                                                     float* __restrict__ out) {
    int g = blockIdx.x;
    __shared__ float pooled[128];
    int t = threadIdx.x;
    if (t < 64) {
        int cnt = gstart[g + 1] - gstart[g];
        pooled[t] = gsum[g * 64 + t] / fmaxf((float)cnt, 1.0f);
    } else {
        pooled[t] = gmax[g * 64 + (t - 64)];
    }
    __syncthreads();
    if (t < 32) {
        float acc = bl[t];
#pragma unroll 8
        for (int k = 0; k < 128; ++k) acc += pooled[k] * Wl[k * 32 + t];
        out[g * 32 + t] = acc;
    }
}

extern "C" void kernel_launch(void* const* d_in, const int* in_sizes, int n_in,
                              void* d_out, int out_size, void* d_ws, size_t ws_size,
                              hipStream_t stream) {
    const float* x        = (const float*)d_in[0];   // 50000 x 128
    const int*   ei       = (const int*)d_in[1];     // 2 x 800000
    const int*   batch    = (const int*)d_in[2];     // 50000
    const float* W1       = (const float*)d_in[3];   // 128 x 64
    const float* b1       = (const float*)d_in[4];
    const float* W2       = (const float*)d_in[5];   // 64 x 64
    const float* b2       = (const float*)d_in[6];
    const float* W3       = (const float*)d_in[7];   // 64 x 64
    const float* b3       = (const float*)d_in[8];
    const float* Wl       = (const float*)d_in[9];   // 128 x 32
    const float* bl       = (const float*)d_in[10];
    float* out = (float*)d_out;

    char* ws = (char*)d_ws;
    int*   cnt      = (int*)ws;                 ws += align256((size_t)N_NODES * 4);
    int*   incl     = (int*)ws;                 ws += align256((size_t)N_NODES * 4);
    int*   bsum     = (int*)ws;                 ws += align256((size_t)SCAN_NB * 4);
    int*   boff     = (int*)ws;                 ws += align256((size_t)SCAN_NB * 4);
    int*   row_ptr  = (int*)ws;                 ws += align256((size_t)(N_NODES + 1) * 4);
    int*   fill_ptr = (int*)ws;                 ws += align256((size_t)N_NODES * 4);
    float* dinv     = (float*)ws;               ws += align256((size_t)N_NODES * 4);
    int*   gstart   = (int*)ws;                 ws += align256((size_t)(N_GRAPHS + 1) * 4);
    float* gsum     = (float*)ws;               ws += align256((size_t)N_GRAPHS * 64 * 4);
    float* gmax     = (float*)ws;               ws += align256((size_t)N_GRAPHS * 64 * 4);
    int*   csr_src  = (int*)ws;                 ws += align256((size_t)N_EDGES * 4);
    unsigned short* hwa = (unsigned short*)ws;  ws += align256((size_t)N_NODES * 64 * 2);
    unsigned short* hwbuf = (unsigned short*)ws; ws += align256((size_t)N_NODES * 64 * 2);
    float* h1       = (float*)ws;               ws += align256((size_t)N_NODES * 64 * 4);

    hipLaunchKernelGGL(zero2, dim3((N_NODES + 2 * N_GRAPHS * 64 + 255) / 256), dim3(256), 0,
                       stream, cnt, N_NODES, (int*)gsum, 2 * N_GRAPHS * 64);
    hipLaunchKernelGGL(deg_kernel, dim3((N_EDGES + 255) / 256), dim3(256), 0, stream, ei, cnt);
    hipLaunchKernelGGL(scan_a, dim3(SCAN_NB), dim3(256), 0, stream, cnt, incl, bsum);
    hipLaunchKernelGGL(scan_b_gstart, dim3(1), dim3(384), 0, stream, bsum, boff, batch, gstart);
    hipLaunchKernelGGL(scan_c, dim3(SCAN_NB), dim3(256), 0, stream,
                       cnt, incl, boff, row_ptr, fill_ptr, dinv);
    hipLaunchKernelGGL(fill_kernel,
                       dim3(FILL_RANGES * ((N_EDGES + 255) / 256)), dim3(256), 0, stream,
                       ei, fill_ptr, csr_src);

    const int mm_grid = (N_NODES + 63) / 64;
    const int agg_grid = (N_NODES + 3) / 4;

    // layer 1 matmul: x(128) @ W1 -> hwa (dinv-scaled, bf16)
    hipLaunchKernelGGL((mfma_matmul<128>), dim3(mm_grid), dim3(256), 0, stream, x, W1, dinv, hwa);
    // fused agg(layer1) + matmul W2 -> hwbuf
    hipLaunchKernelGGL(aggmm_kernel, dim3(agg_grid), dim3(256), 0, stream,
                       hwa, row_ptr, csr_src, dinv, b1, W2, hwbuf);
    // fused agg(layer2) + matmul W3 -> hwa
    hipLaunchKernelGGL(aggmm_kernel, dim3(agg_grid), dim3(256), 0, stream,
                       hwbuf, row_ptr, csr_src, dinv, b2, W3, hwa);
    // final agg (layer3) -> h1 f32
    hipLaunchKernelGGL(agg_kernel, dim3(agg_grid), dim3(256), 0, stream,
                       hwa, row_ptr, csr_src, dinv, b3, h1);

    // two-phase pooling + final linear
    hipLaunchKernelGGL(pool_partial_kernel, dim3((N_NODES + 63) / 64), dim3(256), 0, stream,
                       h1, batch, gsum, gmax);
    hipLaunchKernelGGL(linear_kernel, dim3(N_GRAPHS), dim3(128), 0, stream,
                       gsum, gmax, gstart, Wl, bl, out);
}

// Round 13
// 212.351 us; speedup vs baseline: 1.2708x; 1.2708x over previous
//
#include <hip/hip_runtime.h>
#include <hip/hip_bf16.h>

#define N_NODES 50000
#define N_EDGES 800000
#define N_GRAPHS 64
#define HID 64
#define SCAN_NB 196  // ceil(50000/256)
#define FILL_RANGES 8
#define RANGE_SIZE ((N_NODES + FILL_RANGES - 1) / FILL_RANGES)  // 6250

static inline size_t align256(size_t x) { return (x + 255) & ~(size_t)255; }

typedef __attribute__((ext_vector_type(8))) short short8v;
typedef __attribute__((ext_vector_type(4))) float f32x4;

// bf16 helpers (bit-level, RNE) -- storage compression + MFMA input prep.
__device__ __forceinline__ unsigned short f2bf(float f) {
    unsigned int u = __float_as_uint(f);
    unsigned int r = (u + 0x7fffu + ((u >> 16) & 1u)) >> 16;
    return (unsigned short)r;
}
__device__ __forceinline__ float bf2f(unsigned short h) {
    return __uint_as_float(((unsigned int)h) << 16);
}

// zero two disjoint int arrays in one launch (launch-count reduction)
__global__ void zero2(int* __restrict__ a, int na, int* __restrict__ b, int nb) {
    int i = blockIdx.x * blockDim.x + threadIdx.x;
    if (i < na) a[i] = 0;
    else if (i < na + nb) b[i - na] = 0;
}

// count incoming edges per destination node
__global__ void deg_kernel(const int* __restrict__ ei, int* __restrict__ cnt) {
    int e = blockIdx.x * blockDim.x + threadIdx.x;
    if (e < N_EDGES) atomicAdd(&cnt[ei[N_EDGES + e]], 1);
}

// phase A: per-block (256-wide) inclusive scan of cnt; block totals to bsum
__global__ __launch_bounds__(256) void scan_a(const int* __restrict__ cnt,
                                              int* __restrict__ incl,
                                              int* __restrict__ bsum) {
    __shared__ int sd[256];
    int t = threadIdx.x;
    int i = blockIdx.x * 256 + t;
    int v = (i < N_NODES) ? cnt[i] : 0;
    sd[t] = v;
    __syncthreads();
    for (int off = 1; off < 256; off <<= 1) {
        int u = (t >= off) ? sd[t - off] : 0;
        __syncthreads();
        sd[t] += u;
        __syncthreads();
    }
    if (i < N_NODES) incl[i] = sd[t];
    if (t == 255) bsum[blockIdx.x] = sd[255];
}

// phase B (+gstart fused): threads 0..255 scan the block sums; threads
// 256..320 binary-search gstart (batch sorted). All threads hit every barrier.
__global__ __launch_bounds__(384) void scan_b_gstart(const int* __restrict__ bsum,
                                                     int* __restrict__ boff,
                                                     const int* __restrict__ batch,
                                                     int* __restrict__ gstart) {
    __shared__ int sd[256];
    int t = threadIdx.x;
    int v = 0;
    if (t < 256) {
        v = (t < SCAN_NB) ? bsum[t] : 0;
        sd[t] = v;
    }
    __syncthreads();
    for (int off = 1; off < 256; off <<= 1) {
        int u = (t < 256 && t >= off) ? sd[t - off] : 0;
        __syncthreads();
        if (t < 256) sd[t] += u;
        __syncthreads();
    }
    if (t < SCAN_NB) boff[t] = sd[t] - v;  // exclusive
    if (t >= 256 && t - 256 <= N_GRAPHS) {
        int g = t - 256;
        int lo = 0, hi = N_NODES;
        while (lo < hi) {
            int mid = (lo + hi) >> 1;
            if (batch[mid] < g) lo = mid + 1; else hi = mid;
        }
        gstart[g] = lo;
    }
}

// phase C: writeback row_ptr / fill_ptr / dinv
__global__ void scan_c(const int* __restrict__ cnt, const int* __restrict__ incl,
                       const int* __restrict__ boff, int* __restrict__ row_ptr,
                       int* __restrict__ fill_ptr, float* __restrict__ dinv) {
    int i = blockIdx.x * blockDim.x + threadIdx.x;
    if (i < N_NODES) {
        int c = cnt[i];
        int run = boff[i >> 8] + incl[i];  // inclusive prefix over all nodes
        row_ptr[i + 1] = run;
        fill_ptr[i] = run - c;             // bucket start
        dinv[i] = rsqrtf((float)c + 1.0f);
        if (i == 0) row_ptr[0] = 0;
    }
}

// XCD-partitioned CSR scatter (round-8 lesson: unpartitioned random 4B
// scatter writes cost a 64B line writeback each; partition dst ranges so
// each csr region is written from one XCD and lines stay L2-resident).
__global__ __launch_bounds__(256) void fill_kernel(const int* __restrict__ ei,
                                                   int* __restrict__ fill_ptr,
                                                   int* __restrict__ csr_src) {
    int r = blockIdx.x & (FILL_RANGES - 1);
    int e = (blockIdx.x >> 3) * 256 + threadIdx.x;
    if (e >= N_EDGES) return;
    int dst = ei[N_EDGES + e];
    int lo = r * RANGE_SIZE;
    if (dst >= lo && dst < lo + RANGE_SIZE) {
        int src = ei[e];
        int pos = atomicAdd(&fill_ptr[dst], 1);
        csr_src[pos] = src;
    }
}

// MFMA matmul: hw2 = bf16(dinv * (h @ W)). 3-term hi/lo bf16 split keeps
// error at bf16^2 (~1.6e-5). W fragments pre-swizzled in LDS (conflict-free
// ds_read_b128); A per-lane from global (L3-resident).
// D layout (m89-verified): row=(l>>4)*4+j, col=l&15.
// Round-12 lesson: do NOT fuse this into the gather kernel -- the in-wave
// shfl+LDS matmul costs ~40us/layer vs ~6us for this kernel.
template <int K>
__global__ __launch_bounds__(256) void mfma_matmul(const float* __restrict__ h,
                                                   const float* __restrict__ W,
                                                   const float* __restrict__ dinv,
                                                   unsigned short* __restrict__ hw2) {
    constexpr int NSTEP = K / 32;
    __shared__ unsigned short sWH[NSTEP * 4 * 64 * 8];
    __shared__ unsigned short sWL[NSTEP * 4 * 64 * 8];
    int tid = threadIdx.x;
    int r0 = blockIdx.x * 64;

#pragma unroll 1
    for (int ent = tid; ent < NSTEP * 4 * 64; ent += 256) {
        int lane_e = ent & 63;
        int c = (ent >> 6) & 3;
        int step = ent >> 8;
        int kb = step * 32 + (lane_e >> 4) * 8;
        int n = c * 16 + (lane_e & 15);
#pragma unroll
        for (int j = 0; j < 8; ++j) {
            float f = W[(kb + j) * 64 + n];
            unsigned short hi = f2bf(f);
            sWH[ent * 8 + j] = hi;
            sWL[ent * 8 + j] = f2bf(f - bf2f(hi));
        }
    }
    __syncthreads();

    int lane = tid & 63;
    int wid = tid >> 6;
    int arow = min(r0 + wid * 16 + (lane & 15), N_NODES - 1);  // clamp; write guarded
    const float* ap = h + (size_t)arow * K;
    int klane = (lane >> 4) * 8;

    f32x4 acc[4];
#pragma unroll
    for (int c = 0; c < 4; ++c) acc[c] = (f32x4){0.f, 0.f, 0.f, 0.f};

#pragma unroll 1
    for (int step = 0; step < NSTEP; ++step) {
        int kb = step * 32 + klane;
        float4 f0 = *(const float4*)&ap[kb];
        float4 f1 = *(const float4*)&ap[kb + 4];
        float fv[8] = {f0.x, f0.y, f0.z, f0.w, f1.x, f1.y, f1.z, f1.w};
        short8v ahi, alo;
#pragma unroll
        for (int j = 0; j < 8; ++j) {
            unsigned short hi = f2bf(fv[j]);
            ahi[j] = (short)hi;
            alo[j] = (short)f2bf(fv[j] - bf2f(hi));
        }
#pragma unroll
        for (int c = 0; c < 4; ++c) {
            short8v bh = *(const short8v*)&sWH[((step * 4 + c) * 64 + lane) * 8];
            short8v bl = *(const short8v*)&sWL[((step * 4 + c) * 64 + lane) * 8];
            acc[c] = __builtin_amdgcn_mfma_f32_16x16x32_bf16(ahi, bh, acc[c], 0, 0, 0);
            acc[c] = __builtin_amdgcn_mfma_f32_16x16x32_bf16(alo, bh, acc[c], 0, 0, 0);
            acc[c] = __builtin_amdgcn_mfma_f32_16x16x32_bf16(ahi, bl, acc[c], 0, 0, 0);
        }
    }

    int rb = r0 + wid * 16 + (lane >> 4) * 4;
#pragma unroll
    for (int j = 0; j < 4; ++j) {
        int row = rb + j;
        if (row < N_NODES) {
            float dv = dinv[row];
#pragma unroll
            for (int c = 0; c < 4; ++c) {
                hw2[(size_t)row * 64 + c * 16 + (lane & 15)] = f2bf(dv * acc[c][j]);
            }
        }
    }
}

// per node (one wave): 8 edges in flight per iteration (was 4; agg is
// request-latency-bound -- 2x MLP). lane = 8*grp + gl; each 8-lane group
// fetches a full 128B bf16 row as ushort8 (16B/lane). Edge indices
// pre-loaded coalesced, distributed via shfl with WAVE-UNIFORM trip count
// (round-5 lesson); only the accumulation is predicated.
__global__ __launch_bounds__(256) void agg_kernel(const unsigned short* __restrict__ hw2,
                                                  const int* __restrict__ row_ptr,
                                                  const int* __restrict__ csr_src,
                                                  const float* __restrict__ dinv,
                                                  const float* __restrict__ b,
                                                  float* __restrict__ hout) {
    int node = blockIdx.x * 4 + (threadIdx.x >> 6);
    int lane = threadIdx.x & 63;
    if (node >= N_NODES) return;
    int grp = lane >> 3;   // 0..7 : which edge of the 8-wide batch
    int gl  = lane & 7;    // 0..7 : dims 8*gl .. 8*gl+7
    int s = row_ptr[node], e = row_ptr[node + 1];

    float acc[8] = {0.f, 0.f, 0.f, 0.f, 0.f, 0.f, 0.f, 0.f};
    for (int base = s; base < e; base += 64) {
        int nE = min(64, e - base);                          // wave-uniform
        int msrc = (lane < nE) ? csr_src[base + lane] : 0;   // coalesced
#pragma unroll 2
        for (int i = 0; i < nE; i += 8) {                    // uniform trip count
            int myi = i + grp;                               // <= 63 always
            int src = __shfl(msrc, myi, 64);                 // full-exec shfl
            if (myi < nE) {
                short8v v = *(const short8v*)&hw2[(size_t)src * 64 + gl * 8];
#pragma unroll
                for (int j = 0; j < 8; ++j) acc[j] += bf2f((unsigned short)v[j]);
            }
        }
    }
    // sum the 8 groups' partials (dims aligned across groups)
#pragma unroll
    for (int off = 8; off <= 32; off <<= 1) {
#pragma unroll
        for (int j = 0; j < 8; ++j) acc[j] += __shfl_xor(acc[j], off, 64);
    }
    // self-loop term (hw2 pre-scaled by dinv[row])
    short8v sv = *(const short8v*)&hw2[(size_t)node * 64 + gl * 8];
#pragma unroll
    for (int j = 0; j < 8; ++j) acc[j] += bf2f((unsigned short)sv[j]);

    float di = dinv[node];
    float4 b0 = *(const float4*)&b[gl * 8];
    float4 b1 = *(const float4*)&b[gl * 8 + 4];
    float val[8];
    val[0] = di * acc[0] + b0.x;
    val[1] = di * acc[1] + b0.y;
    val[2] = di * acc[2] + b0.z;
    val[3] = di * acc[3] + b0.w;
    val[4] = di * acc[4] + b1.x;
    val[5] = di * acc[5] + b1.y;
    val[6] = di * acc[6] + b1.z;
    val[7] = di * acc[7] + b1.w;

    float sq = 0.f;
#pragma unroll
    for (int j = 0; j < 8; ++j) sq += val[j] * val[j];
#pragma unroll
    for (int off = 1; off <= 4; off <<= 1) sq += __shfl_xor(sq, off, 64);
    float inv = 1.0f / fmaxf(sqrtf(sq), 1e-12f);

    if (grp == 0) {
        float4 r0, r1;
        r0.x = fmaxf(val[0] * inv, 0.f);
        r0.y = fmaxf(val[1] * inv, 0.f);
        r0.z = fmaxf(val[2] * inv, 0.f);
        r0.w = fmaxf(val[3] * inv, 0.f);
        r1.x = fmaxf(val[4] * inv, 0.f);
        r1.y = fmaxf(val[5] * inv, 0.f);
        r1.z = fmaxf(val[6] * inv, 0.f);
        r1.w = fmaxf(val[7] * inv, 0.f);
        *(float4*)&hout[(size_t)node * 64 + gl * 8] = r0;
        *(float4*)&hout[(size_t)node * 64 + gl * 8 + 4] = r1;
    }
}

// Phase-1 pooling: wave owns 16 consecutive nodes, lane = dim; batch sorted ->
// running (graph,sum,max) with atomic flush on transition. Post-ReLU values
// >= 0 so int-bit atomicMax is order-preserving; init-0 matches the guard.
__global__ __launch_bounds__(256) void pool_partial_kernel(const float* __restrict__ h,
                                                           const int* __restrict__ batch,
                                                           float* __restrict__ gsum,
                                                           float* __restrict__ gmax) {
    int wid = threadIdx.x >> 6, lane = threadIdx.x & 63;
    int i0 = blockIdx.x * 64 + wid * 16;
    if (i0 >= N_NODES) return;
    int i1 = min(i0 + 16, N_NODES);
    int gcur = batch[i0];
    float sum = 0.f, mx = 0.f;
    for (int i = i0; i < i1; ++i) {
        int g = batch[i];
        if (g != gcur) {
            atomicAdd(&gsum[gcur * 64 + lane], sum);
            atomicMax((int*)&gmax[gcur * 64 + lane], __float_as_int(mx));
            sum = 0.f; mx = 0.f; gcur = g;
        }
        float v = h[(size_t)i * 64 + lane];
        sum += v;
        mx = fmaxf(mx, v);
    }
    atomicAdd(&gsum[gcur * 64 + lane], sum);
    atomicMax((int*)&gmax[gcur * 64 + lane], __float_as_int(mx));
}

// Phase-2: one block per graph; mean + concat + 128x32 linear.
__global__ __launch_bounds__(128) void linear_kernel(const float* __restrict__ gsum,
                                                     const float* __restrict__ gmax,
                                                     const int* __restrict__ gstart,
                                                     const float* __restrict__ Wl,
                                                     const float* __restrict__ bl,
                                                     float* __restrict__ out) {
    int g = blockIdx.x;
    __shared__ float pooled[128];
    int t = threadIdx.x;
    if (t < 64) {
        int cnt = gstart[g + 1] - gstart[g];
        pooled[t] = gsum[g * 64 + t] / fmaxf((float)cnt, 1.0f);
    } else {
        pooled[t] = gmax[g * 64 + (t - 64)];
    }
    __syncthreads();
    if (t < 32) {
        float acc = bl[t];
#pragma unroll 8
        for (int k = 0; k < 128; ++k) acc += pooled[k] * Wl[k * 32 + t];
        out[g * 32 + t] = acc;
    }
}

extern "C" void kernel_launch(void* const* d_in, const int* in_sizes, int n_in,
                              void* d_out, int out_size, void* d_ws, size_t ws_size,
                              hipStream_t stream) {
    const float* x        = (const float*)d_in[0];   // 50000 x 128
    const int*   ei       = (const int*)d_in[1];     // 2 x 800000
    const int*   batch    = (const int*)d_in[2];     // 50000
    const float* W1       = (const float*)d_in[3];   // 128 x 64
    const float* b1       = (const float*)d_in[4];
    const float* W2       = (const float*)d_in[5];   // 64 x 64
    const float* b2       = (const float*)d_in[6];
    const float* W3       = (const float*)d_in[7];   // 64 x 64
    const float* b3       = (const float*)d_in[8];
    const float* Wl       = (const float*)d_in[9];   // 128 x 32
    const float* bl       = (const float*)d_in[10];
    float* out = (float*)d_out;

    char* ws = (char*)d_ws;
    int*   cnt      = (int*)ws;                 ws += align256((size_t)N_NODES * 4);
    int*   incl     = (int*)ws;                 ws += align256((size_t)N_NODES * 4);
    int*   bsum     = (int*)ws;                 ws += align256((size_t)SCAN_NB * 4);
    int*   boff     = (int*)ws;                 ws += align256((size_t)SCAN_NB * 4);
    int*   row_ptr  = (int*)ws;                 ws += align256((size_t)(N_NODES + 1) * 4);
    int*   fill_ptr = (int*)ws;                 ws += align256((size_t)N_NODES * 4);
    float* dinv     = (float*)ws;               ws += align256((size_t)N_NODES * 4);
    int*   gstart   = (int*)ws;                 ws += align256((size_t)(N_GRAPHS + 1) * 4);
    float* gsum     = (float*)ws;               ws += align256((size_t)N_GRAPHS * 64 * 4);
    float* gmax     = (float*)ws;               ws += align256((size_t)N_GRAPHS * 64 * 4);
    int*   csr_src  = (int*)ws;                 ws += align256((size_t)N_EDGES * 4);
    unsigned short* hwb = (unsigned short*)ws;  ws += align256((size_t)N_NODES * 64 * 2);
    float* h1       = (float*)ws;               ws += align256((size_t)N_NODES * 64 * 4);
    float* h2       = (float*)ws;               ws += align256((size_t)N_NODES * 64 * 4);

    hipLaunchKernelGGL(zero2, dim3((N_NODES + 2 * N_GRAPHS * 64 + 255) / 256), dim3(256), 0,
                       stream, cnt, N_NODES, (int*)gsum, 2 * N_GRAPHS * 64);
    hipLaunchKernelGGL(deg_kernel, dim3((N_EDGES + 255) / 256), dim3(256), 0, stream, ei, cnt);
    hipLaunchKernelGGL(scan_a, dim3(SCAN_NB), dim3(256), 0, stream, cnt, incl, bsum);
    hipLaunchKernelGGL(scan_b_gstart, dim3(1), dim3(384), 0, stream, bsum, boff, batch, gstart);
    hipLaunchKernelGGL(scan_c, dim3(SCAN_NB), dim3(256), 0, stream,
                       cnt, incl, boff, row_ptr, fill_ptr, dinv);
    hipLaunchKernelGGL(fill_kernel,
                       dim3(FILL_RANGES * ((N_EDGES + 255) / 256)), dim3(256), 0, stream,
                       ei, fill_ptr, csr_src);

    const int mm_grid = (N_NODES + 63) / 64;
    const int agg_grid = (N_NODES + 3) / 4;

    // layer 1: x(128) @ W1 -> hwb (dinv-scaled, bf16); agg -> h1 (f32)
    hipLaunchKernelGGL((mfma_matmul<128>), dim3(mm_grid), dim3(256), 0, stream, x, W1, dinv, hwb);
    hipLaunchKernelGGL(agg_kernel, dim3(agg_grid), dim3(256), 0, stream,
                       hwb, row_ptr, csr_src, dinv, b1, h1);
    // layer 2
    hipLaunchKernelGGL((mfma_matmul<64>), dim3(mm_grid), dim3(256), 0, stream, h1, W2, dinv, hwb);
    hipLaunchKernelGGL(agg_kernel, dim3(agg_grid), dim3(256), 0, stream,
                       hwb, row_ptr, csr_src, dinv, b2, h2);
    // layer 3
    hipLaunchKernelGGL((mfma_matmul<64>), dim3(mm_grid), dim3(256), 0, stream, h2, W3, dinv, hwb);
    hipLaunchKernelGGL(agg_kernel, dim3(agg_grid), dim3(256), 0, stream,
                       hwb, row_ptr, csr_src, dinv, b3, h1);

    // two-phase pooling + final linear
    hipLaunchKernelGGL(pool_partial_kernel, dim3((N_NODES + 63) / 64), dim3(256), 0, stream,
                       h1, batch, gsum, gmax);
    hipLaunchKernelGGL(linear_kernel, dim3(N_GRAPHS), dim3(128), 0, stream,
                       gsum, gmax, gstart, Wl, bl, out);
}